// Round 3
// baseline (349.654 us; speedup 1.0000x reference)
//
#include <hip/hip_runtime.h>

typedef __attribute__((ext_vector_type(8))) short short8;
typedef __attribute__((ext_vector_type(4))) float floatx4;

#define KDIM 1024

__device__ inline float b2f(ushort u) {
    union { uint i; float f; } c; c.i = ((uint)u) << 16; return c.f;
}
__device__ inline ushort f2b(float f) {
    union { uint i; float f; } c; c.f = f;
    uint i = c.i;
    uint r = (i + 0x7FFFu + ((i >> 16) & 1u)) >> 16;
    return (ushort)r;
}

// C[M][N] = A[M][K] * Bw[N][K]^T,  K=1024, fp32 accum via 16x16x32 bf16 MFMA.
// AF32/BF32: source dtype (fp32 converted to bf16 during LDS staging).
// OUTF32: store fp32 (else bf16).
// grid: (N/64, M/64), block 256 (4 waves). Wave w owns cols [w*16, w*16+16).
template <bool AF32, bool BF32, bool OUTF32>
__global__ __launch_bounds__(256) void gemm_bt(const void* __restrict__ Ap,
                                               const void* __restrict__ Bp,
                                               void* __restrict__ Cp,
                                               int M, int N) {
    __shared__ __align__(16) ushort As[64][40];  // +8 pad: 80B row stride
    __shared__ __align__(16) ushort Bs[64][40];
    const int tid = threadIdx.x;
    const int wave = tid >> 6, lane = tid & 63;
    const int quad = lane >> 4, l16 = lane & 15;
    const int m0 = blockIdx.y * 64, n0 = blockIdx.x * 64;

    floatx4 acc[4] = {};

    const int lrow = tid >> 2;            // 0..63
    const int lc8 = (tid & 3) * 8;        // 0,8,16,24
    uint4* asd = (uint4*)&As[lrow][lc8];
    uint4* bsd = (uint4*)&Bs[lrow][lc8];
    const size_t arow = (size_t)(m0 + lrow) * KDIM + lc8;
    const size_t brow = (size_t)(n0 + lrow) * KDIM + lc8;

    for (int kt = 0; kt < KDIM / 32; ++kt) {
        __syncthreads();
        if (AF32) {
            const float* a = (const float*)Ap + arow + kt * 32;
            float4 f0 = *(const float4*)a;
            float4 f1 = *(const float4*)(a + 4);
            ushort u[8] = {f2b(f0.x), f2b(f0.y), f2b(f0.z), f2b(f0.w),
                           f2b(f1.x), f2b(f1.y), f2b(f1.z), f2b(f1.w)};
            *asd = *(const uint4*)u;
        } else {
            *asd = *(const uint4*)((const ushort*)Ap + arow + kt * 32);
        }
        if (BF32) {
            const float* b = (const float*)Bp + brow + kt * 32;
            float4 f0 = *(const float4*)b;
            float4 f1 = *(const float4*)(b + 4);
            ushort u[8] = {f2b(f0.x), f2b(f0.y), f2b(f0.z), f2b(f0.w),
                           f2b(f1.x), f2b(f1.y), f2b(f1.z), f2b(f1.w)};
            *bsd = *(const uint4*)u;
        } else {
            *bsd = *(const uint4*)((const ushort*)Bp + brow + kt * 32);
        }
        __syncthreads();
        short8 bfr = *(const short8*)&Bs[wave * 16 + l16][quad * 8];
#pragma unroll
        for (int rb = 0; rb < 4; ++rb) {
            short8 afr = *(const short8*)&As[rb * 16 + l16][quad * 8];
            acc[rb] = __builtin_amdgcn_mfma_f32_16x16x32_bf16(afr, bfr, acc[rb], 0, 0, 0);
        }
    }
#pragma unroll
    for (int rb = 0; rb < 4; ++rb) {
        const int row = m0 + rb * 16 + quad * 4;
        const int col = n0 + wave * 16 + l16;
#pragma unroll
        for (int r = 0; r < 4; ++r) {
            if (OUTF32) ((float*)Cp)[(size_t)(row + r) * N + col] = acc[rb][r];
            else        ((ushort*)Cp)[(size_t)(row + r) * N + col] = f2b(acc[rb][r]);
        }
    }
}

// RoPE in-place on bf16 Q and K ws buffers [4096][1024] (row=b*2048+s, col=h*64+d).
__global__ __launch_bounds__(256) void rope_k(ushort* __restrict__ q,
                                              ushort* __restrict__ k,
                                              const int* __restrict__ pos) {
    const int idx = blockIdx.x * 256 + threadIdx.x;   // 0..524287
    ushort* t = blockIdx.y ? k : q;
    const int e0 = idx * 8;
    const int row = e0 >> 10;
    const int s = row & 2047;
    const int d0 = e0 & 63;                // even, within head
    const float p = (float)pos[s];

    uint4 raw = *(const uint4*)(t + e0);
    ushort* u = (ushort*)&raw;
#pragma unroll
    for (int j = 0; j < 4; ++j) {
        const int i = (d0 >> 1) + j;       // pair index 0..31
        const float inv = exp2f(-(float)i * (2.0f / 64.0f) * 13.287712379549449f);
        const float ang = p * inv;
        float sn, cs;
        sincosf(ang, &sn, &cs);            // accurate reduction: ang up to ~2047 rad
        const float e = b2f(u[2 * j]);
        const float o = b2f(u[2 * j + 1]);
        u[2 * j]     = f2b(e * cs - o * sn);
        u[2 * j + 1] = f2b(e * sn + o * cs);
    }
    *(uint4*)(t + e0) = raw;
}

// Causal flash attention. Q,K,O: [4096][1024] (row=b*2048+s, col=h*64+d), bf16.
// Vt: [1024][4096] (row=h*64+d, col=b*2048+s), bf16.
// grid: (32 q-tiles, 32 b*h), block 256 (4 waves); wave w owns q rows [w*16, w*16+16).
__global__ __launch_bounds__(256) void attn_k(const ushort* __restrict__ Qg,
                                              const ushort* __restrict__ Kg,
                                              const ushort* __restrict__ Vtg,
                                              ushort* __restrict__ Og) {
    __shared__ __align__(16) ushort Qs[64][72];
    __shared__ __align__(16) ushort Ks[64][72];
    __shared__ __align__(16) ushort Vs[64][72];     // rows = d, cols = s-in-tile
    __shared__ __align__(16) ushort Ps[4][16][72];  // per-wave P tile

    const int tid = threadIdx.x;
    const int wave = tid >> 6, lane = tid & 63;
    const int quad = lane >> 4, l16 = lane & 15;
    const int qt = blockIdx.x;           // q tile 0..31
    const int bh = blockIdx.y;           // 0..31
    const int b = bh >> 4, h = bh & 15;
    const int q0 = qt * 64;

    const int r0 = tid >> 3, c8 = (tid & 7) * 8;
    const int r1 = r0 + 32;

    *(uint4*)&Qs[r0][c8] = *(const uint4*)(Qg + (size_t)(b * 2048 + q0 + r0) * 1024 + h * 64 + c8);
    *(uint4*)&Qs[r1][c8] = *(const uint4*)(Qg + (size_t)(b * 2048 + q0 + r1) * 1024 + h * 64 + c8);
    __syncthreads();
    const short8 aq0 = *(const short8*)&Qs[wave * 16 + l16][quad * 8];
    const short8 aq1 = *(const short8*)&Qs[wave * 16 + l16][32 + quad * 8];

    floatx4 o_acc[4] = {};
    float m_st[4], l_st[4];
#pragma unroll
    for (int r = 0; r < 4; ++r) { m_st[r] = -1e30f; l_st[r] = 0.0f; }
    const int qrow = q0 + wave * 16 + quad * 4;       // + r

    for (int kt = 0; kt <= qt; ++kt) {
        __syncthreads();
        *(uint4*)&Ks[r0][c8] = *(const uint4*)(Kg + (size_t)(b * 2048 + kt * 64 + r0) * 1024 + h * 64 + c8);
        *(uint4*)&Ks[r1][c8] = *(const uint4*)(Kg + (size_t)(b * 2048 + kt * 64 + r1) * 1024 + h * 64 + c8);
        *(uint4*)&Vs[r0][c8] = *(const uint4*)(Vtg + (size_t)(h * 64 + r0) * 4096 + b * 2048 + kt * 64 + c8);
        *(uint4*)&Vs[r1][c8] = *(const uint4*)(Vtg + (size_t)(h * 64 + r1) * 4096 + b * 2048 + kt * 64 + c8);
        __syncthreads();

        // S = Q K^T  (16 x 64 per wave)
        floatx4 sc[4];
#pragma unroll
        for (int cb = 0; cb < 4; ++cb) {
            short8 bk0 = *(const short8*)&Ks[cb * 16 + l16][quad * 8];
            short8 bk1 = *(const short8*)&Ks[cb * 16 + l16][32 + quad * 8];
            floatx4 z = {};
            z = __builtin_amdgcn_mfma_f32_16x16x32_bf16(aq0, bk0, z, 0, 0, 0);
            z = __builtin_amdgcn_mfma_f32_16x16x32_bf16(aq1, bk1, z, 0, 0, 0);
            sc[cb] = z;
        }

        // scale + causal mask + online softmax
        float pvals[4][4], rmax[4];
#pragma unroll
        for (int r = 0; r < 4; ++r) rmax[r] = -1e30f;
        const bool diag = (kt == qt);
#pragma unroll
        for (int cb = 0; cb < 4; ++cb) {
            const int kcol = kt * 64 + cb * 16 + l16;
#pragma unroll
            for (int r = 0; r < 4; ++r) {
                float v = sc[cb][r] * 0.125f;
                if (diag && (kcol > qrow + r)) v = -1e30f;
                pvals[cb][r] = v;
                rmax[r] = fmaxf(rmax[r], v);
            }
        }
#pragma unroll
        for (int off = 1; off < 16; off <<= 1)
#pragma unroll
            for (int r = 0; r < 4; ++r)
                rmax[r] = fmaxf(rmax[r], __shfl_xor(rmax[r], off));

        float alpha[4], rsum[4];
#pragma unroll
        for (int r = 0; r < 4; ++r) {
            const float mn = fmaxf(m_st[r], rmax[r]);
            alpha[r] = __expf(m_st[r] - mn);
            m_st[r] = mn;
            rsum[r] = 0.0f;
        }
#pragma unroll
        for (int cb = 0; cb < 4; ++cb)
#pragma unroll
            for (int r = 0; r < 4; ++r) {
                const float pe = __expf(pvals[cb][r] - m_st[r]);
                pvals[cb][r] = pe;
                rsum[r] += pe;
            }
#pragma unroll
        for (int off = 1; off < 16; off <<= 1)
#pragma unroll
            for (int r = 0; r < 4; ++r)
                rsum[r] += __shfl_xor(rsum[r], off);
#pragma unroll
        for (int r = 0; r < 4; ++r) l_st[r] = l_st[r] * alpha[r] + rsum[r];

        // P -> LDS (C-layout write), then read back in A-layout (per-wave tile)
#pragma unroll
        for (int cb = 0; cb < 4; ++cb)
#pragma unroll
            for (int r = 0; r < 4; ++r)
                Ps[wave][quad * 4 + r][cb * 16 + l16] = f2b(pvals[cb][r]);
        asm volatile("s_waitcnt lgkmcnt(0)" ::: "memory");

#pragma unroll
        for (int cb = 0; cb < 4; ++cb)
#pragma unroll
            for (int r = 0; r < 4; ++r)
                o_acc[cb][r] *= alpha[r];

        const short8 ap0 = *(const short8*)&Ps[wave][l16][quad * 8];
        const short8 ap1 = *(const short8*)&Ps[wave][l16][32 + quad * 8];
#pragma unroll
        for (int cb = 0; cb < 4; ++cb) {
            short8 bv0 = *(const short8*)&Vs[cb * 16 + l16][quad * 8];
            short8 bv1 = *(const short8*)&Vs[cb * 16 + l16][32 + quad * 8];
            o_acc[cb] = __builtin_amdgcn_mfma_f32_16x16x32_bf16(ap0, bv0, o_acc[cb], 0, 0, 0);
            o_acc[cb] = __builtin_amdgcn_mfma_f32_16x16x32_bf16(ap1, bv1, o_acc[cb], 0, 0, 0);
        }
    }

#pragma unroll
    for (int r = 0; r < 4; ++r) l_st[r] = 1.0f / l_st[r];
#pragma unroll
    for (int cb = 0; cb < 4; ++cb) {
        const int col = h * 64 + cb * 16 + l16;
#pragma unroll
        for (int r = 0; r < 4; ++r)
            Og[(size_t)(b * 2048 + qrow + r) * 1024 + col] = f2b(o_acc[cb][r] * l_st[r]);
    }
}

extern "C" void kernel_launch(void* const* d_in, const int* in_sizes, int n_in,
                              void* d_out, int out_size, void* d_ws, size_t ws_size,
                              hipStream_t stream) {
    const void* x  = d_in[0];   // fp32 [2][2048][1024]
    const void* wq = d_in[1];   // fp32 [1024][1024]
    const void* wk = d_in[2];
    const void* wv = d_in[3];
    const void* wo = d_in[4];
    const int* pos = (const int*)d_in[5];

    const size_t NX = (size_t)4096 * 1024;

    // Workspace: exactly 32 MiB of bf16 intermediates.
    ushort* q_ws  = (ushort*)d_ws;           // [4096][1024]
    ushort* k_ws  = q_ws + NX;               // [4096][1024]
    ushort* vt_ws = k_ws + NX;               // [1024][4096]
    ushort* o_ws  = vt_ws + NX;              // [4096][1024]

    // Q = x wq^T ; K = x wk^T  (fp32 in, bf16 out)
    gemm_bt<true, true, false><<<dim3(16, 64), 256, 0, stream>>>(x, wq, q_ws, 4096, 1024);
    gemm_bt<true, true, false><<<dim3(16, 64), 256, 0, stream>>>(x, wk, k_ws, 4096, 1024);
    // Vt = wv x^T -> [1024][4096] = per-head V^T
    gemm_bt<true, true, false><<<dim3(64, 16), 256, 0, stream>>>(wv, x, vt_ws, 1024, 4096);
    // RoPE on Q and K
    rope_k<<<dim3(2048, 2), 256, 0, stream>>>(q_ws, k_ws, pos);
    // causal flash attention -> bf16 O
    attn_k<<<dim3(32, 32), 256, 0, stream>>>(q_ws, k_ws, vt_ws, o_ws);
    // out = O wo^T  (bf16 A, fp32 B, fp32 out)
    gemm_bt<false, true, true><<<dim3(16, 64), 256, 0, stream>>>(o_ws, wo, d_out, 4096, 1024);
}

// Round 4
// 336.938 us; speedup vs baseline: 1.0377x; 1.0377x over previous
//
#include <hip/hip_runtime.h>

typedef __attribute__((ext_vector_type(8))) short short8;
typedef __attribute__((ext_vector_type(4))) short short4v;
typedef __attribute__((ext_vector_type(4))) float floatx4;

__device__ inline float b2f(ushort u) {
    union { uint i; float f; } c; c.i = ((uint)u) << 16; return c.f;
}
__device__ inline ushort f2b(float f) {
    union { uint i; float f; } c; c.f = f;
    uint i = c.i;
    uint r = (i + 0x7FFFu + ((i >> 16) & 1u)) >> 16;
    return (ushort)r;
}

__device__ __forceinline__ void load_lds16(const ushort* g, ushort* l) {
    __builtin_amdgcn_global_load_lds((const __attribute__((address_space(1))) void*)g,
                                     (__attribute__((address_space(3))) void*)l, 16, 0, 0);
}

// fp32 -> bf16 conversion, 8 elems/thread.
__global__ __launch_bounds__(256) void cvt_k(const float* __restrict__ in,
                                             ushort* __restrict__ out, int n) {
    const int i = (blockIdx.x * 256 + threadIdx.x) * 8;
    if (i >= n) return;
    float4 f0 = *(const float4*)(in + i);
    float4 f1 = *(const float4*)(in + i + 4);
    ushort u[8] = {f2b(f0.x), f2b(f0.y), f2b(f0.z), f2b(f0.w),
                   f2b(f1.x), f2b(f1.y), f2b(f1.z), f2b(f1.w)};
    *(uint4*)(out + i) = *(const uint4*)u;
}

// m97-style 128x128 GEMM body, K=1024, BK=32, 4 waves (2x2 of 64x64).
// C[M][N] = A[M][1024] * B[N][1024]^T. LDS unpadded (global_load_lds contiguity).
template <bool OUTF32>
__device__ __forceinline__ void gemm_body(ushort* As, ushort* Bs,
                                          const ushort* __restrict__ A,
                                          const ushort* __restrict__ B,
                                          void* __restrict__ C,
                                          int N, int m0, int n0) {
    const int tid = threadIdx.x;
    const int wave = tid >> 6, lane = tid & 63;
    const int quad = lane >> 4, l16 = lane & 15;
    const int wm = (wave >> 1) * 64, wn = (wave & 1) * 64;

    floatx4 acc[4][4] = {};

    const int c1 = tid, c2 = tid + 256;   // 16B chunk ids; chunk c: row c>>2, k-col (c&3)*8
    const ushort* ga1 = A + (size_t)(m0 + (c1 >> 2)) * 1024 + (c1 & 3) * 8;
    const ushort* ga2 = A + (size_t)(m0 + (c2 >> 2)) * 1024 + (c2 & 3) * 8;
    const ushort* gb1 = B + (size_t)(n0 + (c1 >> 2)) * 1024 + (c1 & 3) * 8;
    const ushort* gb2 = B + (size_t)(n0 + (c2 >> 2)) * 1024 + (c2 & 3) * 8;
    ushort* la1 = As + c1 * 8;
    ushort* la2 = As + c2 * 8;
    ushort* lb1 = Bs + c1 * 8;
    ushort* lb2 = Bs + c2 * 8;

    for (int kt = 0; kt < 32; ++kt) {
        __syncthreads();
        load_lds16(ga1 + kt * 32, la1);
        load_lds16(ga2 + kt * 32, la2);
        load_lds16(gb1 + kt * 32, lb1);
        load_lds16(gb2 + kt * 32, lb2);
        __syncthreads();
        short8 af[4], bf[4];
#pragma unroll
        for (int i = 0; i < 4; ++i) {
            af[i] = *(const short8*)(As + (wm + i * 16 + l16) * 32 + quad * 8);
            bf[i] = *(const short8*)(Bs + (wn + i * 16 + l16) * 32 + quad * 8);
        }
#pragma unroll
        for (int mi = 0; mi < 4; ++mi)
#pragma unroll
            for (int ni = 0; ni < 4; ++ni)
                acc[mi][ni] = __builtin_amdgcn_mfma_f32_16x16x32_bf16(af[mi], bf[ni], acc[mi][ni], 0, 0, 0);
    }
#pragma unroll
    for (int mi = 0; mi < 4; ++mi) {
        const int row = m0 + wm + mi * 16 + quad * 4;
#pragma unroll
        for (int ni = 0; ni < 4; ++ni) {
            const int col = n0 + wn + ni * 16 + l16;
#pragma unroll
            for (int r = 0; r < 4; ++r) {
                if (OUTF32) ((float*)C)[(size_t)(row + r) * N + col] = acc[mi][ni][r];
                else        ((ushort*)C)[(size_t)(row + r) * N + col] = f2b(acc[mi][ni][r]);
            }
        }
    }
}

// Fused Q/K/Vt GEMM: 768 blocks (3/CU). Jobs share the same x m-panel per CU.
__global__ __launch_bounds__(256) void gemm_qkv(const ushort* __restrict__ xb,
                                                const ushort* __restrict__ wqb,
                                                const ushort* __restrict__ wkb,
                                                const ushort* __restrict__ wvb,
                                                ushort* __restrict__ q,
                                                ushort* __restrict__ k,
                                                ushort* __restrict__ vt) {
    __shared__ __align__(16) ushort As[4096], Bs[4096];
    const int blk = blockIdx.x;
    const int job = blk >> 8, r = blk & 255;
    const ushort *A, *B;
    ushort* C;
    int N, m0, n0;
    if (job == 0)      { A = xb;  B = wqb; C = q;  N = 1024; m0 = (r >> 3) * 128; n0 = (r & 7) * 128; }
    else if (job == 1) { A = xb;  B = wkb; C = k;  N = 1024; m0 = (r >> 3) * 128; n0 = (r & 7) * 128; }
    else               { A = wvb; B = xb;  C = vt; N = 4096; m0 = (r & 7) * 128;  n0 = (r >> 3) * 128; }
    gemm_body<false>(As, Bs, A, B, C, N, m0, n0);
}

// Output projection: C fp32 = O[4096][1024] * wo[1024][1024]^T
__global__ __launch_bounds__(256) void gemm_o(const ushort* __restrict__ A,
                                              const ushort* __restrict__ B,
                                              float* __restrict__ C) {
    __shared__ __align__(16) ushort As[4096], Bs[4096];
    gemm_body<true>(As, Bs, A, B, C, 1024, blockIdx.y * 128, blockIdx.x * 128);
}

// RoPE in-place on bf16 Q,K [4096][1024] (row=b*2048+s, col=h*64+d).
__global__ __launch_bounds__(256) void rope_k(ushort* __restrict__ q,
                                              ushort* __restrict__ k,
                                              const int* __restrict__ pos) {
    const int idx = blockIdx.x * 256 + threadIdx.x;
    ushort* t = blockIdx.y ? k : q;
    const int e0 = idx * 8;
    const int s = (e0 >> 10) & 2047;
    const int d0 = e0 & 63;
    const float p = (float)pos[s];
    uint4 raw = *(const uint4*)(t + e0);
    ushort* u = (ushort*)&raw;
#pragma unroll
    for (int j = 0; j < 4; ++j) {
        const int i = (d0 >> 1) + j;
        const float inv = exp2f(-(float)i * (2.0f / 64.0f) * 13.287712379549449f);
        float sn, cs;
        sincosf(p * inv, &sn, &cs);
        const float e = b2f(u[2 * j]);
        const float o = b2f(u[2 * j + 1]);
        u[2 * j]     = f2b(e * cs - o * sn);
        u[2 * j + 1] = f2b(e * sn + o * cs);
    }
    *(uint4*)(t + e0) = raw;
}

// Barrier-free causal flash attention. Each wave owns 16 q-rows.
// S^T = K Q^T (col=q=lane&15 -> softmax per-lane), O^T = V^T P^T (P stays in regs).
// grid 1024: blk -> t=blk>>5, bh=blk&31; qg=(t<16)?t:47-t (per-CU work ~const).
__global__ __launch_bounds__(256) void attn_k(const ushort* __restrict__ Qg,
                                              const ushort* __restrict__ Kg,
                                              const ushort* __restrict__ Vtg,
                                              ushort* __restrict__ Og) {
    const int tid = threadIdx.x;
    const int wave = tid >> 6, lane = tid & 63;
    const int quad = lane >> 4, l16 = lane & 15;
    const int blk = blockIdx.x;
    const int t = blk >> 5, bh = blk & 31;
    const int qg = (t < 16) ? t : 47 - t;          // 64-row q-tile index, 0..31
    const int b = bh >> 4, h = bh & 15;
    const int bq = b * 2048;
    const int q0 = qg * 64 + wave * 16;            // wave's first q-row (in seq)
    const int wl = wave * 16 + l16;                // q offset within 64-tile, for mask

    // Q fragments (B-operand of S^T MFMA): lane holds Q[q0+l16][quad*8 + j]
    const ushort* qrow = Qg + (size_t)(bq + q0 + l16) * 1024 + h * 64 + quad * 8;
    const short8 qf0 = *(const short8*)qrow;
    const short8 qf1 = *(const short8*)(qrow + 32);

    floatx4 od[4] = {};                            // O^T tiles: d=db*16+quad*4+r, q=l16
    float m_st = -1e30f, l_st = 0.0f;              // per q=l16 scalars

    for (int kt = 0; kt <= qg; ++kt) {
        const int s0 = bq + kt * 64;
        // V^T fragments (A-operand, 16x16x16): V^T[db*16+l16][cb*16+quad*4+j]
        short4v vf[4][4];
#pragma unroll
        for (int db = 0; db < 4; ++db)
#pragma unroll
            for (int cb = 0; cb < 4; ++cb)
                vf[db][cb] = *(const short4v*)(Vtg + (size_t)(h * 64 + db * 16 + l16) * 4096
                                               + s0 + cb * 16 + quad * 4);
        // S^T = K Q^T
        floatx4 st[4];
#pragma unroll
        for (int cb = 0; cb < 4; ++cb) {
            const ushort* krow = Kg + (size_t)(s0 + cb * 16 + l16) * 1024 + h * 64 + quad * 8;
            short8 kf0 = *(const short8*)krow;
            short8 kf1 = *(const short8*)(krow + 32);
            floatx4 z = {};
            z = __builtin_amdgcn_mfma_f32_16x16x32_bf16(kf0, qf0, z, 0, 0, 0);
            z = __builtin_amdgcn_mfma_f32_16x16x32_bf16(kf1, qf1, z, 0, 0, 0);
            st[cb] = z;
        }

        // softmax: stats per q=l16. In-lane over 16 s-values, then 2 shuffles.
        const bool diag = (kt == qg);
        float pv[4][4];
        float mx = -1e30f;
#pragma unroll
        for (int cb = 0; cb < 4; ++cb) {
            const int scb = cb * 16 + quad * 4;
#pragma unroll
            for (int r = 0; r < 4; ++r) {
                float v = st[cb][r] * 0.125f;
                if (diag && (scb + r > wl)) v = -1e30f;
                pv[cb][r] = v;
                mx = fmaxf(mx, v);
            }
        }
        mx = fmaxf(mx, __shfl_xor(mx, 16));
        mx = fmaxf(mx, __shfl_xor(mx, 32));
        const float mn = fmaxf(m_st, mx);
        const float alpha = __expf(m_st - mn);
        m_st = mn;
        float sum = 0.0f;
#pragma unroll
        for (int cb = 0; cb < 4; ++cb)
#pragma unroll
            for (int r = 0; r < 4; ++r) {
                const float p = __expf(pv[cb][r] - mn);
                pv[cb][r] = p;
                sum += p;
            }
        sum += __shfl_xor(sum, 16);
        sum += __shfl_xor(sum, 32);
        l_st = l_st * alpha + sum;

        // P^T fragments (B-operand of 16x16x16) direct from registers
        short4v pb[4];
#pragma unroll
        for (int cb = 0; cb < 4; ++cb) {
            short4v pk;
#pragma unroll
            for (int r = 0; r < 4; ++r) pk[r] = (short)f2b(pv[cb][r]);
            pb[cb] = pk;
        }
#pragma unroll
        for (int db = 0; db < 4; ++db) {
            od[db] *= alpha;
#pragma unroll
            for (int cb = 0; cb < 4; ++cb)
                od[db] = __builtin_amdgcn_mfma_f32_16x16x16bf16_1k(vf[db][cb], pb[cb], od[db], 0, 0, 0);
        }
    }

    const float linv = 1.0f / l_st;
    ushort* orow = Og + (size_t)(bq + q0 + l16) * 1024 + h * 64 + quad * 4;
#pragma unroll
    for (int db = 0; db < 4; ++db) {
        uint2 w;
        w.x = (uint)f2b(od[db][0] * linv) | ((uint)f2b(od[db][1] * linv) << 16);
        w.y = (uint)f2b(od[db][2] * linv) | ((uint)f2b(od[db][3] * linv) << 16);
        *(uint2*)(orow + db * 16) = w;
    }
}

extern "C" void kernel_launch(void* const* d_in, const int* in_sizes, int n_in,
                              void* d_out, int out_size, void* d_ws, size_t ws_size,
                              hipStream_t stream) {
    const float* x  = (const float*)d_in[0];
    const float* wq = (const float*)d_in[1];
    const float* wk = (const float*)d_in[2];
    const float* wv = (const float*)d_in[3];
    const float* wo = (const float*)d_in[4];
    const int* pos  = (const int*)d_in[5];

    const size_t NX = (size_t)4096 * 1024;   // 4M
    const size_t NW = (size_t)1024 * 1024;   // 1M

    // d_ws (32 MiB): bf16 q, k, vt, o
    ushort* q_ws  = (ushort*)d_ws;
    ushort* k_ws  = q_ws + NX;
    ushort* vt_ws = k_ws + NX;
    ushort* o_ws  = vt_ws + NX;
    // d_out (16 MB fp32) doubles as bf16 scratch until the final GEMM:
    ushort* xb  = (ushort*)d_out;            // 8 MB
    ushort* wqb = xb + NX;                   // 2 MB
    ushort* wkb = wqb + NW;
    ushort* wvb = wkb + NW;

    cvt_k<<<dim3(2048), 256, 0, stream>>>(x, xb, (int)NX);
    cvt_k<<<dim3(512), 256, 0, stream>>>(wq, wqb, (int)NW);
    cvt_k<<<dim3(512), 256, 0, stream>>>(wk, wkb, (int)NW);
    cvt_k<<<dim3(512), 256, 0, stream>>>(wv, wvb, (int)NW);

    gemm_qkv<<<dim3(768), 256, 0, stream>>>(xb, wqb, wkb, wvb, q_ws, k_ws, vt_ws);
    rope_k<<<dim3(2048, 2), 256, 0, stream>>>(q_ws, k_ws, pos);
    attn_k<<<dim3(1024), 256, 0, stream>>>(q_ws, k_ws, vt_ws, o_ws);

    // wo -> bf16 into q_ws (dead after attention); then out = O wo^T (fp32)
    cvt_k<<<dim3(512), 256, 0, stream>>>(wo, q_ws, (int)NW);
    gemm_o<<<dim3(8, 32), 256, 0, stream>>>(o_ws, q_ws, (float*)d_out);
}

// Round 5
// 250.008 us; speedup vs baseline: 1.3986x; 1.3477x over previous
//
#include <hip/hip_runtime.h>

typedef __attribute__((ext_vector_type(8))) short short8;
typedef __attribute__((ext_vector_type(4))) short short4v;
typedef __attribute__((ext_vector_type(4))) float floatx4;

__device__ inline float b2f(ushort u) {
    union { uint i; float f; } c; c.i = ((uint)u) << 16; return c.f;
}
__device__ inline ushort f2b(float f) {
    union { uint i; float f; } c; c.f = f;
    uint i = c.i;
    uint r = (i + 0x7FFFu + ((i >> 16) & 1u)) >> 16;
    return (ushort)r;
}

__device__ __forceinline__ void load_lds16(const ushort* g, ushort* l) {
    __builtin_amdgcn_global_load_lds((const __attribute__((address_space(1))) void*)g,
                                     (__attribute__((address_space(3))) void*)l, 16, 0, 0);
}

// Fused fp32->bf16 conversion of x, wq, wk, wv (one launch).
__global__ __launch_bounds__(256) void cvt4_k(const float* __restrict__ x,
                                              const float* __restrict__ wq,
                                              const float* __restrict__ wk,
                                              const float* __restrict__ wv,
                                              ushort* __restrict__ xb,
                                              ushort* __restrict__ wqb,
                                              ushort* __restrict__ wkb,
                                              ushort* __restrict__ wvb) {
    const int blk = blockIdx.x;
    const float* in; ushort* out; int base;
    if (blk < 2048)      { in = x;  out = xb;  base = blk; }
    else if (blk < 2560) { in = wq; out = wqb; base = blk - 2048; }
    else if (blk < 3072) { in = wk; out = wkb; base = blk - 2560; }
    else                 { in = wv; out = wvb; base = blk - 3072; }
    const int i = (base * 256 + threadIdx.x) * 8;
    float4 f0 = *(const float4*)(in + i);
    float4 f1 = *(const float4*)(in + i + 4);
    ushort u[8] = {f2b(f0.x), f2b(f0.y), f2b(f0.z), f2b(f0.w),
                   f2b(f1.x), f2b(f1.y), f2b(f1.z), f2b(f1.w)};
    *(uint4*)(out + i) = *(const uint4*)u;
}

// fp32 -> bf16, single tensor (for wo).
__global__ __launch_bounds__(256) void cvt_k(const float* __restrict__ in,
                                             ushort* __restrict__ out, int n) {
    const int i = (blockIdx.x * 256 + threadIdx.x) * 8;
    if (i >= n) return;
    float4 f0 = *(const float4*)(in + i);
    float4 f1 = *(const float4*)(in + i + 4);
    ushort u[8] = {f2b(f0.x), f2b(f0.y), f2b(f0.z), f2b(f0.w),
                   f2b(f1.x), f2b(f1.y), f2b(f1.z), f2b(f1.w)};
    *(uint4*)(out + i) = *(const uint4*)u;
}

// m97-style 128x128 GEMM body, K=1024, BK=32, 4 waves (2x2 of 64x64).
template <bool OUTF32>
__device__ __forceinline__ void gemm_body(ushort* As, ushort* Bs,
                                          const ushort* __restrict__ A,
                                          const ushort* __restrict__ B,
                                          void* __restrict__ C,
                                          int N, int m0, int n0) {
    const int tid = threadIdx.x;
    const int wave = tid >> 6, lane = tid & 63;
    const int quad = lane >> 4, l16 = lane & 15;
    const int wm = (wave >> 1) * 64, wn = (wave & 1) * 64;

    floatx4 acc[4][4] = {};

    const int c1 = tid, c2 = tid + 256;
    const ushort* ga1 = A + (size_t)(m0 + (c1 >> 2)) * 1024 + (c1 & 3) * 8;
    const ushort* ga2 = A + (size_t)(m0 + (c2 >> 2)) * 1024 + (c2 & 3) * 8;
    const ushort* gb1 = B + (size_t)(n0 + (c1 >> 2)) * 1024 + (c1 & 3) * 8;
    const ushort* gb2 = B + (size_t)(n0 + (c2 >> 2)) * 1024 + (c2 & 3) * 8;
    ushort* la1 = As + c1 * 8;
    ushort* la2 = As + c2 * 8;
    ushort* lb1 = Bs + c1 * 8;
    ushort* lb2 = Bs + c2 * 8;

    for (int kt = 0; kt < 32; ++kt) {
        __syncthreads();
        load_lds16(ga1 + kt * 32, la1);
        load_lds16(ga2 + kt * 32, la2);
        load_lds16(gb1 + kt * 32, lb1);
        load_lds16(gb2 + kt * 32, lb2);
        __syncthreads();
        short8 af[4], bf[4];
#pragma unroll
        for (int i = 0; i < 4; ++i) {
            af[i] = *(const short8*)(As + (wm + i * 16 + l16) * 32 + quad * 8);
            bf[i] = *(const short8*)(Bs + (wn + i * 16 + l16) * 32 + quad * 8);
        }
#pragma unroll
        for (int mi = 0; mi < 4; ++mi)
#pragma unroll
            for (int ni = 0; ni < 4; ++ni)
                acc[mi][ni] = __builtin_amdgcn_mfma_f32_16x16x32_bf16(af[mi], bf[ni], acc[mi][ni], 0, 0, 0);
    }
#pragma unroll
    for (int mi = 0; mi < 4; ++mi) {
        const int row = m0 + wm + mi * 16 + quad * 4;
#pragma unroll
        for (int ni = 0; ni < 4; ++ni) {
            const int col = n0 + wn + ni * 16 + l16;
#pragma unroll
            for (int r = 0; r < 4; ++r) {
                if (OUTF32) ((float*)C)[(size_t)(row + r) * N + col] = acc[mi][ni][r];
                else        ((ushort*)C)[(size_t)(row + r) * N + col] = f2b(acc[mi][ni][r]);
            }
        }
    }
}

// Fused Q/K/Vt GEMM: 768 blocks (3/CU).
__global__ __launch_bounds__(256) void gemm_qkv(const ushort* __restrict__ xb,
                                                const ushort* __restrict__ wqb,
                                                const ushort* __restrict__ wkb,
                                                const ushort* __restrict__ wvb,
                                                ushort* __restrict__ q,
                                                ushort* __restrict__ k,
                                                ushort* __restrict__ vt) {
    __shared__ __align__(16) ushort As[4096], Bs[4096];
    const int blk = blockIdx.x;
    const int job = blk >> 8, r = blk & 255;
    const ushort *A, *B;
    ushort* C;
    int N, m0, n0;
    if (job == 0)      { A = xb;  B = wqb; C = q;  N = 1024; m0 = (r >> 3) * 128; n0 = (r & 7) * 128; }
    else if (job == 1) { A = xb;  B = wkb; C = k;  N = 1024; m0 = (r >> 3) * 128; n0 = (r & 7) * 128; }
    else               { A = wvb; B = xb;  C = vt; N = 4096; m0 = (r & 7) * 128;  n0 = (r >> 3) * 128; }
    gemm_body<false>(As, Bs, A, B, C, N, m0, n0);
}

// Output projection: C fp32 = O[4096][1024] * wo[1024][1024]^T
__global__ __launch_bounds__(256) void gemm_o(const ushort* __restrict__ A,
                                              const ushort* __restrict__ B,
                                              float* __restrict__ C) {
    __shared__ __align__(16) ushort As[4096], Bs[4096];
    gemm_body<true>(As, Bs, A, B, C, 1024, blockIdx.y * 128, blockIdx.x * 128);
}

// RoPE in-place on bf16 Q,K [4096][1024]. Fast sin/cos: angle<=2047 rad, fp32
// reduction error ~1e-4 rad << bf16 eps.
__global__ __launch_bounds__(256) void rope_k(ushort* __restrict__ q,
                                              ushort* __restrict__ k,
                                              const int* __restrict__ pos) {
    const int idx = blockIdx.x * 256 + threadIdx.x;
    ushort* t = blockIdx.y ? k : q;
    const int e0 = idx * 8;
    const int s = (e0 >> 10) & 2047;
    const int d0 = e0 & 63;
    const float p = (float)pos[s];
    uint4 raw = *(const uint4*)(t + e0);
    ushort* u = (ushort*)&raw;
#pragma unroll
    for (int j = 0; j < 4; ++j) {
        const int i = (d0 >> 1) + j;
        const float inv = exp2f(-(float)i * (2.0f / 64.0f) * 13.287712379549449f);
        const float ang = p * inv;
        const float sn = __sinf(ang), cs = __cosf(ang);
        const float e = b2f(u[2 * j]);
        const float o = b2f(u[2 * j + 1]);
        u[2 * j]     = f2b(e * cs - o * sn);
        u[2 * j + 1] = f2b(e * sn + o * cs);
    }
    *(uint4*)(t + e0) = raw;
}

// Causal flash attention, LDS-staged + double-buffered.
// S^T = K Q^T (q=lane&15 -> per-lane softmax), P in regs, O^T = V^T P^T.
// LDS tiles chunk-swizzled: chunk(row, j) stored at row*8 + ((j+row)&7), so
// 128B-row-stride fragment reads stay <=4-way bank aliased while satisfying
// global_load_lds's contiguous lane->LDS mapping (we permute GLOBAL addrs).
// grid 1024: t=blk&31 -> qg balanced pairing; bh=blk>>5.
__global__ __launch_bounds__(256) void attn_k(const ushort* __restrict__ Qg,
                                              const ushort* __restrict__ Kg,
                                              const ushort* __restrict__ Vtg,
                                              ushort* __restrict__ Og) {
    __shared__ __align__(16) ushort Ks[2][4096];   // [s][d] swizzled, 8KB each
    __shared__ __align__(16) ushort Vs[2][4096];   // [d][s] swizzled

    const int tid = threadIdx.x;
    const int wave = tid >> 6, lane = tid & 63;
    const int quad = lane >> 4, l16 = lane & 15;
    const int blk = blockIdx.x;
    const int t = blk & 31, bh = blk >> 5;
    const int qg = (t & 1) ? (31 - (t >> 1)) : (t >> 1);   // consecutive blocks balance
    const int b = bh >> 4, h = bh & 15;
    const int bq = b * 2048;
    const int q0 = qg * 64 + wave * 16;
    const int wl = wave * 16 + l16;                // q offset within 64-tile (mask)

    // Q fragments (B-operand): lane holds Q[q0+l16][quad*8+j]
    const ushort* qrow = Qg + (size_t)(bq + q0 + l16) * 1024 + h * 64 + quad * 8;
    const short8 qf0 = *(const short8*)qrow;
    const short8 qf1 = *(const short8*)(qrow + 32);

    // staging: thread covers chunks cA=tid, cB=tid+256 of each 512-chunk tile
    const int cA = tid, cB = tid + 256;
    const int sA = cA >> 3, jKA = ((cA & 7) - sA) & 7;
    const int sB = cB >> 3, jKB = ((cB & 7) - sB) & 7;
    const ushort* kgA = Kg + (size_t)(bq + sA) * 1024 + h * 64 + jKA * 8;
    const ushort* kgB = Kg + (size_t)(bq + sB) * 1024 + h * 64 + jKB * 8;
    const int dA = sA, jVA = jKA;                  // same inversion for V
    const int dB = sB, jVB = jKB;
    const ushort* vgA = Vtg + (size_t)(h * 64 + dA) * 4096 + bq + jVA * 8;
    const ushort* vgB = Vtg + (size_t)(h * 64 + dB) * 4096 + bq + jVB * 8;

    floatx4 od[4] = {};
    float m_st = -1e30f, l_st = 0.0f;

    // prologue: stage tile 0 into buffer 0
    load_lds16(kgA, &Ks[0][cA * 8]);
    load_lds16(kgB, &Ks[0][cB * 8]);
    load_lds16(vgA, &Vs[0][cA * 8]);
    load_lds16(vgB, &Vs[0][cB * 8]);
    __syncthreads();

    for (int kt = 0; kt <= qg; ++kt) {
        const int cur = kt & 1;
        if (kt < qg) {                             // prefetch next tile
            const int nxt = cur ^ 1;
            load_lds16(kgA + (size_t)(kt + 1) * 65536, &Ks[nxt][cA * 8]);
            load_lds16(kgB + (size_t)(kt + 1) * 65536, &Ks[nxt][cB * 8]);
            load_lds16(vgA + (kt + 1) * 64, &Vs[nxt][cA * 8]);
            load_lds16(vgB + (kt + 1) * 64, &Vs[nxt][cB * 8]);
        }
        const ushort* kb = Ks[cur];
        const ushort* vb = Vs[cur];

        // S^T = K Q^T
        floatx4 st[4];
#pragma unroll
        for (int cb = 0; cb < 4; ++cb) {
            const int s = cb * 16 + l16;
            const int ch0 = s * 8 + ((quad + s) & 7);
            const int ch1 = s * 8 + ((quad + 4 + s) & 7);
            short8 kf0 = *(const short8*)(kb + ch0 * 8);
            short8 kf1 = *(const short8*)(kb + ch1 * 8);
            floatx4 z = {};
            z = __builtin_amdgcn_mfma_f32_16x16x32_bf16(kf0, qf0, z, 0, 0, 0);
            z = __builtin_amdgcn_mfma_f32_16x16x32_bf16(kf1, qf1, z, 0, 0, 0);
            st[cb] = z;
        }

        // per-lane softmax (q = l16), 2 shuffles across the quad replicas
        const bool diag = (kt == qg);
        float pv[4][4];
        float mx = -1e30f;
#pragma unroll
        for (int cb = 0; cb < 4; ++cb) {
            const int scb = cb * 16 + quad * 4;
#pragma unroll
            for (int r = 0; r < 4; ++r) {
                float v = st[cb][r] * 0.125f;
                if (diag && (scb + r > wl)) v = -1e30f;
                pv[cb][r] = v;
                mx = fmaxf(mx, v);
            }
        }
        mx = fmaxf(mx, __shfl_xor(mx, 16));
        mx = fmaxf(mx, __shfl_xor(mx, 32));
        const float mn = fmaxf(m_st, mx);
        const float alpha = __expf(m_st - mn);
        m_st = mn;
        float sum = 0.0f;
#pragma unroll
        for (int cb = 0; cb < 4; ++cb)
#pragma unroll
            for (int r = 0; r < 4; ++r) {
                const float p = __expf(pv[cb][r] - mn);
                pv[cb][r] = p;
                sum += p;
            }
        sum += __shfl_xor(sum, 16);
        sum += __shfl_xor(sum, 32);
        l_st = l_st * alpha + sum;

        // P^T fragments (B-operand of 16x16x16) straight from registers
        short4v pb[4];
#pragma unroll
        for (int cb = 0; cb < 4; ++cb) {
            short4v pk;
#pragma unroll
            for (int r = 0; r < 4; ++r) pk[r] = (short)f2b(pv[cb][r]);
            pb[cb] = pk;
        }
        // O^T += V^T P^T
#pragma unroll
        for (int db = 0; db < 4; ++db) {
            od[db] *= alpha;
            const int d = db * 16 + l16;
#pragma unroll
            for (int cb = 0; cb < 4; ++cb) {
                const int j = cb * 2 + (quad >> 1);
                const int ch = d * 8 + ((j + d) & 7);
                short4v vf = *(const short4v*)(vb + ch * 8 + (quad & 1) * 4);
                od[db] = __builtin_amdgcn_mfma_f32_16x16x16bf16_1k(vf, pb[cb], od[db], 0, 0, 0);
            }
        }
        __syncthreads();   // reads of cur done + prefetch drained (compiler vmcnt)
    }

    const float linv = 1.0f / l_st;
    ushort* orow = Og + (size_t)(bq + q0 + l16) * 1024 + h * 64 + quad * 4;
#pragma unroll
    for (int db = 0; db < 4; ++db) {
        uint2 w;
        w.x = (uint)f2b(od[db][0] * linv) | ((uint)f2b(od[db][1] * linv) << 16);
        w.y = (uint)f2b(od[db][2] * linv) | ((uint)f2b(od[db][3] * linv) << 16);
        *(uint2*)(orow + db * 16) = w;
    }
}

extern "C" void kernel_launch(void* const* d_in, const int* in_sizes, int n_in,
                              void* d_out, int out_size, void* d_ws, size_t ws_size,
                              hipStream_t stream) {
    const float* x  = (const float*)d_in[0];
    const float* wq = (const float*)d_in[1];
    const float* wk = (const float*)d_in[2];
    const float* wv = (const float*)d_in[3];
    const float* wo = (const float*)d_in[4];
    const int* pos  = (const int*)d_in[5];

    const size_t NX = (size_t)4096 * 1024;
    const size_t NW = (size_t)1024 * 1024;

    ushort* q_ws  = (ushort*)d_ws;          // 8 MB each, 32 MiB total
    ushort* k_ws  = q_ws + NX;
    ushort* vt_ws = k_ws + NX;
    ushort* o_ws  = vt_ws + NX;
    // d_out doubles as bf16 scratch until the final GEMM
    ushort* xb  = (ushort*)d_out;
    ushort* wqb = xb + NX;
    ushort* wkb = wqb + NW;
    ushort* wvb = wkb + NW;

    cvt4_k<<<dim3(3584), 256, 0, stream>>>(x, wq, wk, wv, xb, wqb, wkb, wvb);
    gemm_qkv<<<dim3(768), 256, 0, stream>>>(xb, wqb, wkb, wvb, q_ws, k_ws, vt_ws);
    rope_k<<<dim3(2048, 2), 256, 0, stream>>>(q_ws, k_ws, pos);
    attn_k<<<dim3(1024), 256, 0, stream>>>(q_ws, k_ws, vt_ws, o_ws);
    cvt_k<<<dim3(512), 256, 0, stream>>>(wo, q_ws, (int)NW);   // q_ws dead now
    gemm_o<<<dim3(8, 32), 256, 0, stream>>>(o_ws, q_ws, (float*)d_out);
}